// Round 4
// baseline (597.035 us; speedup 1.0000x reference)
//
#include <hip/hip_runtime.h>
#include <math.h>

#define B_    16
#define N_    1024
#define G_    32      // blocks per batch (R9: was 16)
#define NW    8       // waves per block
#define ITERS 100
#define SLABF4 288    // float4s per slab: 256 + 32 pad (one per 8) -> bank spread

// ws layout: [cnt: B_*ITERS u32, pad to 8192][mu_den: 4*B_*N_ f32][nug: B_*N_ f32]
#define MUDEN_OFF   8192
#define MUDEN_BYTES (4 * B_ * N_ * 4)
#define NUG_OFF     (MUDEN_OFF + MUDEN_BYTES)
#define ZERO_BYTES  NUG_OFF     // cnt + all 4 mu_den buffers start at 0

__device__ __forceinline__ float fast_div(float num, float den) {
    float r = __builtin_amdgcn_rcpf(den);
    r = r * (2.0f - den * r);      // one Newton step -> ~full fp32 accuracy
    return num * r;
}

// Full 64-lane wave sum via DPP (zero DS-pipe ops, pure VALU). Proven correct
// R1-R3 (passed, absmax 1.19e-7). row_shr:1/2/4/8 builds 16-lane row sums in
// lane 15 of each row; row_bcast:15 + row_bcast:31 fold rows into lane 63.
__device__ __forceinline__ float wave_sum64(float x) {
#define DPP_ADD(ctrl)                                                   \
    x += __int_as_float(__builtin_amdgcn_update_dpp(                    \
            0, __float_as_int(x), ctrl, 0xf, 0xf, false));
    DPP_ADD(0x111)  // row_shr:1
    DPP_ADD(0x112)  // row_shr:2
    DPP_ADD(0x114)  // row_shr:4
    DPP_ADD(0x118)  // row_shr:8
    DPP_ADD(0x142)  // row_bcast:15
    DPP_ADD(0x143)  // row_bcast:31
#undef DPP_ADD
    return __int_as_float(__builtin_amdgcn_readlane(__float_as_int(x), 63));
}

// R9 = R8's proven phases, re-geometried for latency overlap:
//   - 512 blocks x 512 threads (2 blocks/CU co-resident): while one block
//     stalls at the device-barrier poll / syncthreads, the other block's 8
//     waves keep issuing. R8 was 1 block/CU -> all 16 waves phase-locked
//     (VALUBusy 43%, DS 42%, no overlap).
//   - slab stored as float4 with position Q+(Q>>3) (pad 1-in-8): Phase-B
//     write AND gather read are conflict-free b128; float4 component ch maps
//     to column Q+256*ch, so the gather's 4 atomics are at tid+256k --
//     lane-contiguous per wave-instr (R7 lesson: stride-16B atomics = 4x
//     HBM write amplification; contiguous = whole lines).
//   - residency audit (no deadlock): LDS 40KB -> 4 blk/CU; launch_bounds
//     (512,4) caps VGPR<=128 -> >=2 blk/CU; capacity >= grid -> all of a
//     batch's 32 blocks co-resident.
// Ordering (validated R4/R5/R8): __syncthreads() drains vmcnt per wave before
// s_barrier, so atomics are at the L2 coherence point before tid 0's arrival
// add; readers use coherent atomic loads only after the poll sees 32 arrivals.
__global__ __launch_bounds__(512, 4)
void sinkhorn_kernel(const float* __restrict__ C, float* __restrict__ out,
                     float* __restrict__ mu_den, float* __restrict__ nug,
                     unsigned int* __restrict__ cnt)
{
    __shared__ float4 part4[NW * SLABF4];   // 36 KB: padded per-wave slabs
    __shared__ float  mu_s[N_];             // 4 KB: current mu

    const int tid = threadIdx.x;
    const int w   = tid >> 6;        // wave 0..7 -> 4-row group
    const int l   = tid & 63;
    // XCD-affinity swizzle: batch b's 32 blocks share bid%8 -> same XCD L2
    const int bid = blockIdx.x;
    const int xx = bid & 7, ss = bid >> 3;       // ss: 0..63
    const int b = xx + ((ss >> 5) << 3);         // 0..15
    const int g = ss & 31;                       // 0..31: row-group in batch
    const int row0 = 32 * g + 4 * w;
    const float cons = 1.0f / 1024.0f;

    // ---- one-time: U tile = exp(-C/eps), columns 4*l + j + 256*ch ----
    float u[4][16];
    {
        const float* Cb = C + (size_t)b * N_ * N_ + (size_t)row0 * N_;
        #pragma unroll
        for (int rr = 0; rr < 4; ++rr)
            #pragma unroll
            for (int ch = 0; ch < 4; ++ch) {
                float4 cv = *(const float4*)(Cb + (size_t)rr * N_ + 4 * l + 256 * ch);
                u[rr][4*ch+0] = expf(-20.0f * cv.x);
                u[rr][4*ch+1] = expf(-20.0f * cv.y);
                u[rr][4*ch+2] = expf(-20.0f * cv.z);
                u[rr][4*ch+3] = expf(-20.0f * cv.w);
            }
    }

    mu_s[tid]       = cons;
    mu_s[tid + 512] = cons;
    __syncthreads();

    for (int it = 0; it < ITERS; ++it) {
        // ---- Phase A: s_i = sum_j U_ij * mu_j (4x ds_read_b128) ----
        float a0 = 0.f, a1 = 0.f, a2 = 0.f, a3 = 0.f;
        #pragma unroll
        for (int ch = 0; ch < 4; ++ch) {
            float4 mv = *(const float4*)&mu_s[4 * l + 256 * ch];
            a0 += u[0][4*ch+0]*mv.x + u[0][4*ch+1]*mv.y + u[0][4*ch+2]*mv.z + u[0][4*ch+3]*mv.w;
            a1 += u[1][4*ch+0]*mv.x + u[1][4*ch+1]*mv.y + u[1][4*ch+2]*mv.z + u[1][4*ch+3]*mv.w;
            a2 += u[2][4*ch+0]*mv.x + u[2][4*ch+1]*mv.y + u[2][4*ch+2]*mv.z + u[2][4*ch+3]*mv.w;
            a3 += u[3][4*ch+0]*mv.x + u[3][4*ch+1]*mv.y + u[3][4*ch+2]*mv.z + u[3][4*ch+3]*mv.w;
        }
        a0 = wave_sum64(a0);
        a1 = wave_sum64(a1);
        a2 = wave_sum64(a2);
        a3 = wave_sum64(a3);
        float nu0 = fast_div(cons, a0);
        float nu1 = fast_div(cons, a1);
        float nu2 = fast_div(cons, a2);
        float nu3 = fast_div(cons, a3);

        if (it == ITERS - 1 && l < 4) {   // publish final nu chunk (coherent)
            float nv = (l == 0) ? nu0 : (l == 1) ? nu1 : (l == 2) ? nu2 : nu3;
            __hip_atomic_store(&nug[b * N_ + row0 + l], nv,
                               __ATOMIC_RELAXED, __HIP_MEMORY_SCOPE_AGENT);
        }

        // ---- Phase B: per-wave partials -> padded slab (4x ds_write_b128) --
        // float4 Q=4l+j holds columns Q+256*ch in components ch=0..3;
        // position Q+(Q>>3) spreads bank-groups -> conflict-free b128.
        // (no sync needed before this: iter it-1's gather reads finished
        //  before S2 of it-1 < here)
        #pragma unroll
        for (int j = 0; j < 4; ++j) {
            float4 p;
            p.x = u[0][ 0+j]*nu0 + u[1][ 0+j]*nu1 + u[2][ 0+j]*nu2 + u[3][ 0+j]*nu3;
            p.y = u[0][ 4+j]*nu0 + u[1][ 4+j]*nu1 + u[2][ 4+j]*nu2 + u[3][ 4+j]*nu3;
            p.z = u[0][ 8+j]*nu0 + u[1][ 8+j]*nu1 + u[2][ 8+j]*nu2 + u[3][ 8+j]*nu3;
            p.w = u[0][12+j]*nu0 + u[1][12+j]*nu1 + u[2][12+j]*nu2 + u[3][12+j]*nu3;
            const int Q = 4 * l + j;
            part4[w * SLABF4 + Q + (Q >> 3)] = p;
        }
        __syncthreads();   // S1: slabs complete

        // gather: 256 threads x 8 b128 reads (conflict-free), then 4 atomics
        // at tid+256k -- lane-contiguous per wave-instr (whole cache lines)
        const int buf = it & 3;
        if (tid < 256) {
            const int qq = tid + (tid >> 3);
            float4 s4 = {0.f, 0.f, 0.f, 0.f};
            #pragma unroll
            for (int w2 = 0; w2 < NW; ++w2) {
                float4 v = part4[w2 * SLABF4 + qq];
                s4.x += v.x; s4.y += v.y; s4.z += v.z; s4.w += v.w;
            }
            float* md = &mu_den[((size_t)buf * B_ + b) * N_];
            unsafeAtomicAdd(md + tid,       s4.x);
            unsafeAtomicAdd(md + tid + 256, s4.y);
            unsafeAtomicAdd(md + tid + 512, s4.z);
            unsafeAtomicAdd(md + tid + 768, s4.w);
        }

        // ---- fence-free device barrier among the 32 blocks of batch b ----
        __syncthreads();   // S2: each wave's vmcnt(0) -> adds at coherence pt
        if (tid == 0) {
            unsigned int* c = &cnt[b * ITERS + it];
            __hip_atomic_fetch_add(c, 1u, __ATOMIC_RELAXED, __HIP_MEMORY_SCOPE_AGENT);
            while (__hip_atomic_load(c, __ATOMIC_RELAXED, __HIP_MEMORY_SCOPE_AGENT) < G_)
                __builtin_amdgcn_s_sleep(1);
        }
        __syncthreads();   // S3

        // ---- single readback -> new mu; zero the buffer for iter it+2 ----
        {
            const float* mdb = &mu_den[((size_t)buf * B_ + b) * N_];
            float den0 = __hip_atomic_load(mdb + tid,
                                           __ATOMIC_RELAXED, __HIP_MEMORY_SCOPE_AGENT);
            float den1 = __hip_atomic_load(mdb + tid + 512,
                                           __ATOMIC_RELAXED, __HIP_MEMORY_SCOPE_AGENT);
            mu_s[tid]       = fast_div(cons, den0);
            mu_s[tid + 512] = fast_div(cons, den1);
        }
        if (tid < 32)   // my block's 1/32 share of the buffer reused at it+2
            __hip_atomic_store(&mu_den[((size_t)((it + 2) & 3) * B_ + b) * N_ + 32 * g + tid],
                               0.0f, __ATOMIC_RELAXED, __HIP_MEMORY_SCOPE_AGENT);
        __syncthreads();   // S4: mu_s ready for next phase A
    }

    // ---- epilogue: T_ij = mu_i * U_ij * nu_j (float4 stores) ----
    float mu_i[4];
    #pragma unroll
    for (int rr = 0; rr < 4; ++rr)
        mu_i[rr] = mu_s[row0 + rr];          // broadcast read

    float* ob = out + (size_t)b * N_ * N_ + (size_t)row0 * N_;
    #pragma unroll
    for (int ch = 0; ch < 4; ++ch) {
        const int cbase = b * N_ + 4 * l + 256 * ch;
        float4 nuv;
        nuv.x = __hip_atomic_load(&nug[cbase + 0], __ATOMIC_RELAXED, __HIP_MEMORY_SCOPE_AGENT);
        nuv.y = __hip_atomic_load(&nug[cbase + 1], __ATOMIC_RELAXED, __HIP_MEMORY_SCOPE_AGENT);
        nuv.z = __hip_atomic_load(&nug[cbase + 2], __ATOMIC_RELAXED, __HIP_MEMORY_SCOPE_AGENT);
        nuv.w = __hip_atomic_load(&nug[cbase + 3], __ATOMIC_RELAXED, __HIP_MEMORY_SCOPE_AGENT);
        #pragma unroll
        for (int rr = 0; rr < 4; ++rr) {
            float4 t;
            t.x = mu_i[rr] * u[rr][4*ch+0] * nuv.x;
            t.y = mu_i[rr] * u[rr][4*ch+1] * nuv.y;
            t.z = mu_i[rr] * u[rr][4*ch+2] * nuv.z;
            t.w = mu_i[rr] * u[rr][4*ch+3] * nuv.w;
            *(float4*)(ob + (size_t)rr * N_ + 4 * l + 256 * ch) = t;
        }
    }
}

extern "C" void kernel_launch(void* const* d_in, const int* in_sizes, int n_in,
                              void* d_out, int out_size, void* d_ws, size_t ws_size,
                              hipStream_t stream) {
    const float* C = (const float*)d_in[2];     // (B, N, N); x,y unused
    float* out = (float*)d_out;

    unsigned char* ws = (unsigned char*)d_ws;
    unsigned int* cnt = (unsigned int*)ws;
    float* mu_den = (float*)(ws + MUDEN_OFF);
    float* nug    = (float*)(ws + NUG_OFF);

    // cnt + mu_den buffers must start at zero (buffers 2,3 are re-zeroed
    // in-kernel during iters 0,1 as part of the rotation anyway)
    hipMemsetAsync(ws, 0, ZERO_BYTES, stream);
    hipLaunchKernelGGL(sinkhorn_kernel, dim3(512), dim3(512), 0, stream,
                       C, out, mu_den, nug, cnt);
}

// Round 5
// 550.528 us; speedup vs baseline: 1.0845x; 1.0845x over previous
//
#include <hip/hip_runtime.h>
#include <math.h>

#define B_    16
#define N_    1024
#define G_    16      // blocks per batch
#define ITERS 100

// ws layout: [cnt: B_*ITERS u32, pad to 8192][mu_den: 4*B_*N_ f32][nug: B_*N_ f32]
#define MUDEN_OFF   8192
#define MUDEN_BYTES (4 * B_ * N_ * 4)
#define NUG_OFF     (MUDEN_OFF + MUDEN_BYTES)
#define ZERO_BYTES  NUG_OFF     // cnt + all 4 mu_den buffers start at 0

__device__ __forceinline__ float fast_div(float num, float den) {
    float r = __builtin_amdgcn_rcpf(den);
    r = r * (2.0f - den * r);      // one Newton step -> ~full fp32 accuracy
    return num * r;
}

// Full 64-lane wave sum via DPP (zero DS-pipe ops, pure VALU). Proven correct
// R1-R4 (passed, absmax 1.19e-7). row_shr:1/2/4/8 builds 16-lane row sums in
// lane 15 of each row; row_bcast:15 + row_bcast:31 fold rows into lane 63.
__device__ __forceinline__ float wave_sum64(float x) {
#define DPP_ADD(ctrl)                                                   \
    x += __int_as_float(__builtin_amdgcn_update_dpp(                    \
            0, __float_as_int(x), ctrl, 0xf, 0xf, false));
    DPP_ADD(0x111)  // row_shr:1
    DPP_ADD(0x112)  // row_shr:2
    DPP_ADD(0x114)  // row_shr:4
    DPP_ADD(0x118)  // row_shr:8
    DPP_ADD(0x142)  // row_bcast:15
    DPP_ADD(0x143)  // row_bcast:31
#undef DPP_ADD
    return __int_as_float(__builtin_amdgcn_readlane(__float_as_int(x), 63));
}

// R10 = R8 (proven 308us kernel, 0 bank conflicts) with ONLY the gather
// changed to a b128 bounce. R9 lessons encoded:
//   - Phase-B slab writes stay lane-contiguous float4 (R9's permuted layout
//     caused 6.5M bank conflicts via stride-64B float4 writes).
//   - 1 block/CU, 16 blocks/batch (R9's 2-block/CU geometry = convoy, not
//     overlap: same-phase blocks re-sync at every device barrier).
// Gather: 4 waves x 16 ds_read_b128 (lane-contiguous, conflict-free) sum the
// 16 slabs -> colsum (4KB LDS) -> extra barrier -> 1024 threads each issue
// ONE contiguous atomic from colsum[tid] (identical atomic pattern & summation
// order to R8 -> bit-identical result). DS/iter: 3113 -> ~2450 cyc.
// Ordering (validated R4/R5/R8): __syncthreads() drains vmcnt per wave before
// s_barrier, so atomics are at the L2 coherence point before tid 0's arrival
// add; readers use coherent atomic loads only after the poll sees 16 arrivals.
__global__ __launch_bounds__(1024, 4)
void sinkhorn_kernel(const float* __restrict__ C, float* __restrict__ out,
                     float* __restrict__ mu_den, float* __restrict__ nug,
                     unsigned int* __restrict__ cnt)
{
    __shared__ float4 part4[16 * 256];   // 64 KB: per-wave column-partial slabs
    __shared__ float4 colsum4[256];      // 4 KB: cross-wave column sums
    __shared__ float  mu_s[N_];          // 4 KB: current mu

    const int tid = threadIdx.x;
    const int w   = tid >> 6;        // wave 0..15 -> 4-row group
    const int l   = tid & 63;
    // XCD-affinity swizzle: batch b's 16 blocks share bid%8 -> same XCD L2
    const int bid = blockIdx.x;
    const int xx = bid & 7, ss = bid >> 3;
    const int b = xx + ((ss >> 4) << 3);
    const int g = ss & 15;
    const int row0 = 64 * g + 4 * w;
    const float cons = 1.0f / 1024.0f;

    // ---- one-time: U tile = exp(-C/eps), columns 4*l + s + 256*ch ----
    float u[4][16];
    {
        const float* Cb = C + (size_t)b * N_ * N_ + (size_t)row0 * N_;
        #pragma unroll
        for (int rr = 0; rr < 4; ++rr)
            #pragma unroll
            for (int ch = 0; ch < 4; ++ch) {
                float4 cv = *(const float4*)(Cb + (size_t)rr * N_ + 4 * l + 256 * ch);
                u[rr][4*ch+0] = expf(-20.0f * cv.x);
                u[rr][4*ch+1] = expf(-20.0f * cv.y);
                u[rr][4*ch+2] = expf(-20.0f * cv.z);
                u[rr][4*ch+3] = expf(-20.0f * cv.w);
            }
    }

    mu_s[tid] = cons;
    __syncthreads();

    for (int it = 0; it < ITERS; ++it) {
        // ---- Phase A: s_i = sum_j U_ij * mu_j (4x ds_read_b128) ----
        float a0 = 0.f, a1 = 0.f, a2 = 0.f, a3 = 0.f;
        #pragma unroll
        for (int ch = 0; ch < 4; ++ch) {
            float4 mv = *(const float4*)&mu_s[4 * l + 256 * ch];
            a0 += u[0][4*ch+0]*mv.x + u[0][4*ch+1]*mv.y + u[0][4*ch+2]*mv.z + u[0][4*ch+3]*mv.w;
            a1 += u[1][4*ch+0]*mv.x + u[1][4*ch+1]*mv.y + u[1][4*ch+2]*mv.z + u[1][4*ch+3]*mv.w;
            a2 += u[2][4*ch+0]*mv.x + u[2][4*ch+1]*mv.y + u[2][4*ch+2]*mv.z + u[2][4*ch+3]*mv.w;
            a3 += u[3][4*ch+0]*mv.x + u[3][4*ch+1]*mv.y + u[3][4*ch+2]*mv.z + u[3][4*ch+3]*mv.w;
        }
        a0 = wave_sum64(a0);
        a1 = wave_sum64(a1);
        a2 = wave_sum64(a2);
        a3 = wave_sum64(a3);
        float nu0 = fast_div(cons, a0);
        float nu1 = fast_div(cons, a1);
        float nu2 = fast_div(cons, a2);
        float nu3 = fast_div(cons, a3);

        if (it == ITERS - 1 && l < 4) {   // publish final nu chunk (coherent)
            float nv = (l == 0) ? nu0 : (l == 1) ? nu1 : (l == 2) ? nu2 : nu3;
            __hip_atomic_store(&nug[b * N_ + row0 + l], nv,
                               __ATOMIC_RELAXED, __HIP_MEMORY_SCOPE_AGENT);
        }

        // ---- Phase B: per-wave column partials -> slab (4x ds_write_b128,
        //      lane-contiguous: lane l writes float4 index w*256+l+64*ch) ----
        // (no sync needed before this: iter it-1's gather reads finished
        //  before S2 of it-1 < here; part4[] and mu_s[] are separate arrays)
        #pragma unroll
        for (int ch = 0; ch < 4; ++ch) {
            float4 p;
            p.x = u[0][4*ch+0]*nu0 + u[1][4*ch+0]*nu1 + u[2][4*ch+0]*nu2 + u[3][4*ch+0]*nu3;
            p.y = u[0][4*ch+1]*nu0 + u[1][4*ch+1]*nu1 + u[2][4*ch+1]*nu2 + u[3][4*ch+1]*nu3;
            p.z = u[0][4*ch+2]*nu0 + u[1][4*ch+2]*nu1 + u[2][4*ch+2]*nu2 + u[3][4*ch+2]*nu3;
            p.w = u[0][4*ch+3]*nu0 + u[1][4*ch+3]*nu1 + u[2][4*ch+3]*nu2 + u[3][4*ch+3]*nu3;
            part4[w * 256 + l + 64 * ch] = p;
        }
        __syncthreads();   // S1: slabs complete

        // ---- b128 gather: 4 waves sum 16 slabs (64x ds_read_b128 total,
        //      lane-contiguous, conflict-free) -> colsum bounce ----
        if (tid < 256) {
            float4 s4 = {0.f, 0.f, 0.f, 0.f};
            #pragma unroll
            for (int w2 = 0; w2 < 16; ++w2) {
                float4 v = part4[w2 * 256 + tid];
                s4.x += v.x; s4.y += v.y; s4.z += v.z; s4.w += v.w;
            }
            colsum4[tid] = s4;
        }
        __syncthreads();   // S1b: colsum ready

        // ONE contiguous f32 atomic per thread (identical pattern to R8:
        // wave's 64 atomics cover 4 whole cache lines)
        const int buf = it & 3;
        unsafeAtomicAdd(&mu_den[((size_t)buf * B_ + b) * N_ + tid],
                        ((const float*)colsum4)[tid]);

        // ---- fence-free device barrier among the 16 blocks of batch b ----
        __syncthreads();   // S2: each wave's vmcnt(0) -> adds at coherence pt
        if (tid == 0) {
            unsigned int* c = &cnt[b * ITERS + it];
            __hip_atomic_fetch_add(c, 1u, __ATOMIC_RELAXED, __HIP_MEMORY_SCOPE_AGENT);
            while (__hip_atomic_load(c, __ATOMIC_RELAXED, __HIP_MEMORY_SCOPE_AGENT) < G_)
                __builtin_amdgcn_s_sleep(1);
        }
        __syncthreads();   // S3

        // ---- single readback -> new mu; zero the buffer for iter it+2 ----
        {
            float den = __hip_atomic_load(&mu_den[((size_t)buf * B_ + b) * N_ + tid],
                                          __ATOMIC_RELAXED, __HIP_MEMORY_SCOPE_AGENT);
            mu_s[tid] = fast_div(cons, den);
        }
        if (tid < 64)   // my block's 1/16 share of the buffer reused at it+2
            __hip_atomic_store(&mu_den[((size_t)((it + 2) & 3) * B_ + b) * N_ + 64 * g + tid],
                               0.0f, __ATOMIC_RELAXED, __HIP_MEMORY_SCOPE_AGENT);
        __syncthreads();   // S4: mu_s ready for next phase A
    }

    // ---- epilogue: T_ij = mu_i * U_ij * nu_j (float4 stores) ----
    float mu_i[4];
    #pragma unroll
    for (int rr = 0; rr < 4; ++rr)
        mu_i[rr] = mu_s[row0 + rr];          // broadcast read

    float* ob = out + (size_t)b * N_ * N_ + (size_t)row0 * N_;
    #pragma unroll
    for (int ch = 0; ch < 4; ++ch) {
        const int cbase = b * N_ + 4 * l + 256 * ch;
        float4 nuv;
        nuv.x = __hip_atomic_load(&nug[cbase + 0], __ATOMIC_RELAXED, __HIP_MEMORY_SCOPE_AGENT);
        nuv.y = __hip_atomic_load(&nug[cbase + 1], __ATOMIC_RELAXED, __HIP_MEMORY_SCOPE_AGENT);
        nuv.z = __hip_atomic_load(&nug[cbase + 2], __ATOMIC_RELAXED, __HIP_MEMORY_SCOPE_AGENT);
        nuv.w = __hip_atomic_load(&nug[cbase + 3], __ATOMIC_RELAXED, __HIP_MEMORY_SCOPE_AGENT);
        #pragma unroll
        for (int rr = 0; rr < 4; ++rr) {
            float4 t;
            t.x = mu_i[rr] * u[rr][4*ch+0] * nuv.x;
            t.y = mu_i[rr] * u[rr][4*ch+1] * nuv.y;
            t.z = mu_i[rr] * u[rr][4*ch+2] * nuv.z;
            t.w = mu_i[rr] * u[rr][4*ch+3] * nuv.w;
            *(float4*)(ob + (size_t)rr * N_ + 4 * l + 256 * ch) = t;
        }
    }
}

extern "C" void kernel_launch(void* const* d_in, const int* in_sizes, int n_in,
                              void* d_out, int out_size, void* d_ws, size_t ws_size,
                              hipStream_t stream) {
    const float* C = (const float*)d_in[2];     // (B, N, N); x,y unused
    float* out = (float*)d_out;

    unsigned char* ws = (unsigned char*)d_ws;
    unsigned int* cnt = (unsigned int*)ws;
    float* mu_den = (float*)(ws + MUDEN_OFF);
    float* nug    = (float*)(ws + NUG_OFF);

    // cnt + mu_den buffers must start at zero (buffers 2,3 are re-zeroed
    // in-kernel during iters 0,1 as part of the rotation anyway)
    hipMemsetAsync(ws, 0, ZERO_BYTES, stream);
    hipLaunchKernelGGL(sinkhorn_kernel, dim3(256), dim3(1024), 0, stream,
                       C, out, mu_den, nug, cnt);
}

// Round 6
// 405.830 us; speedup vs baseline: 1.4711x; 1.3566x over previous
//
#include <hip/hip_runtime.h>
#include <math.h>

#define B_    16
#define N_    1024
#define G_    16      // blocks per batch
#define ITERS 100

// ws layout: [flags: B_*64 u32 (one 256B-padded flag line per batch), pad to
//            8192][mu_den: 4*B_*N_ f32][nug: B_*N_ f32]
#define MUDEN_OFF   8192
#define MUDEN_BYTES (4 * B_ * N_ * 4)
#define NUG_OFF     (MUDEN_OFF + MUDEN_BYTES)
#define ZERO_BYTES  NUG_OFF     // flags + all 4 mu_den buffers start at 0

__device__ __forceinline__ float fast_div(float num, float den) {
    float r = __builtin_amdgcn_rcpf(den);
    r = r * (2.0f - den * r);      // one Newton step -> ~full fp32 accuracy
    return num * r;
}

// Full 64-lane wave sum via DPP (zero DS-pipe ops, pure VALU). Proven correct
// R1-R5 (passed, absmax 1.19e-7). row_shr:1/2/4/8 builds 16-lane row sums in
// lane 15 of each row; row_bcast:15 + row_bcast:31 fold rows into lane 63.
__device__ __forceinline__ float wave_sum64(float x) {
#define DPP_ADD(ctrl)                                                   \
    x += __int_as_float(__builtin_amdgcn_update_dpp(                    \
            0, __float_as_int(x), ctrl, 0xf, 0xf, false));
    DPP_ADD(0x111)  // row_shr:1
    DPP_ADD(0x112)  // row_shr:2
    DPP_ADD(0x114)  // row_shr:4
    DPP_ADD(0x118)  // row_shr:8
    DPP_ADD(0x142)  // row_bcast:15
    DPP_ADD(0x143)  // row_bcast:31
#undef DPP_ADD
    return __int_as_float(__builtin_amdgcn_readlane(__float_as_int(x), 63));
}

// R11 = R8 (proven 308us: b128 phase A/B, DPP reduce, scalar wide gather,
// contiguous atomics) with ONLY the device barrier changed:
//   counter-RMW + tid0-poll + S3   -->   flag-vector barrier:
//   - arrival: ONE relaxed store of (it+1) to flags[b][g] (16 distinct words
//     in one line -- no same-address RMW serialization at the L2 slice)
//   - detection: EVERY wave polls independently; lanes 0-15 load the 16
//     flags in a single wave-instr, __ballot until all >= it+1 (values are
//     monotonic, so no per-iteration reset needed). No S3 barrier: each wave
//     proceeds to its own readback chunk the moment the condition holds.
// R10 lesson kept: gather stays wide (all 16 waves, scalar b32) -- narrow
// b128 gathers are latency-bound; LDS-BW arithmetic shows two-stage b128
// versions cancel their own gain.
// Ordering (validated R4/R5/R8): __syncthreads() S2 drains vmcnt per wave, so
// each block's mu_den atomics (and the it+2 zero-store, drained by the NEXT
// S2) are at the coherence point before its flag store; readers load mu_den
// only after observing all 16 flags >= it+1.
__global__ __launch_bounds__(1024, 4)
void sinkhorn_kernel(const float* __restrict__ C, float* __restrict__ out,
                     float* __restrict__ mu_den, float* __restrict__ nug,
                     unsigned int* __restrict__ flags)
{
    __shared__ float part[16 * 1024];   // 64 KB: per-wave column-partial slabs
    __shared__ float mu_s[N_];          // 4 KB: current mu

    const int tid = threadIdx.x;
    const int w   = tid >> 6;        // wave 0..15 -> 4-row group
    const int l   = tid & 63;
    // XCD-affinity swizzle: batch b's 16 blocks share bid%8 -> same XCD L2
    const int bid = blockIdx.x;
    const int xx = bid & 7, ss = bid >> 3;
    const int b = xx + ((ss >> 4) << 3);
    const int g = ss & 15;
    const int row0 = 64 * g + 4 * w;
    const float cons = 1.0f / 1024.0f;

    // ---- one-time: U tile = exp(-C/eps), columns 4*l + s + 256*ch ----
    float u[4][16];
    {
        const float* Cb = C + (size_t)b * N_ * N_ + (size_t)row0 * N_;
        #pragma unroll
        for (int rr = 0; rr < 4; ++rr)
            #pragma unroll
            for (int ch = 0; ch < 4; ++ch) {
                float4 cv = *(const float4*)(Cb + (size_t)rr * N_ + 4 * l + 256 * ch);
                u[rr][4*ch+0] = expf(-20.0f * cv.x);
                u[rr][4*ch+1] = expf(-20.0f * cv.y);
                u[rr][4*ch+2] = expf(-20.0f * cv.z);
                u[rr][4*ch+3] = expf(-20.0f * cv.w);
            }
    }

    mu_s[tid] = cons;
    __syncthreads();

    for (int it = 0; it < ITERS; ++it) {
        // ---- Phase A: s_i = sum_j U_ij * mu_j (4x ds_read_b128) ----
        float a0 = 0.f, a1 = 0.f, a2 = 0.f, a3 = 0.f;
        #pragma unroll
        for (int ch = 0; ch < 4; ++ch) {
            float4 mv = *(const float4*)&mu_s[4 * l + 256 * ch];
            a0 += u[0][4*ch+0]*mv.x + u[0][4*ch+1]*mv.y + u[0][4*ch+2]*mv.z + u[0][4*ch+3]*mv.w;
            a1 += u[1][4*ch+0]*mv.x + u[1][4*ch+1]*mv.y + u[1][4*ch+2]*mv.z + u[1][4*ch+3]*mv.w;
            a2 += u[2][4*ch+0]*mv.x + u[2][4*ch+1]*mv.y + u[2][4*ch+2]*mv.z + u[2][4*ch+3]*mv.w;
            a3 += u[3][4*ch+0]*mv.x + u[3][4*ch+1]*mv.y + u[3][4*ch+2]*mv.z + u[3][4*ch+3]*mv.w;
        }
        a0 = wave_sum64(a0);
        a1 = wave_sum64(a1);
        a2 = wave_sum64(a2);
        a3 = wave_sum64(a3);
        float nu0 = fast_div(cons, a0);
        float nu1 = fast_div(cons, a1);
        float nu2 = fast_div(cons, a2);
        float nu3 = fast_div(cons, a3);

        if (it == ITERS - 1 && l < 4) {   // publish final nu chunk (coherent)
            float nv = (l == 0) ? nu0 : (l == 1) ? nu1 : (l == 2) ? nu2 : nu3;
            __hip_atomic_store(&nug[b * N_ + row0 + l], nv,
                               __ATOMIC_RELAXED, __HIP_MEMORY_SCOPE_AGENT);
        }

        // ---- Phase B: per-wave column partials -> slab (4x ds_write_b128,
        //      lane-contiguous) ----
        // (no sync needed before this: iter it-1's gather reads finished
        //  before S2 of it-1 < here; part[] and mu_s[] are separate arrays)
        #pragma unroll
        for (int ch = 0; ch < 4; ++ch) {
            float4 p;
            p.x = u[0][4*ch+0]*nu0 + u[1][4*ch+0]*nu1 + u[2][4*ch+0]*nu2 + u[3][4*ch+0]*nu3;
            p.y = u[0][4*ch+1]*nu0 + u[1][4*ch+1]*nu1 + u[2][4*ch+1]*nu2 + u[3][4*ch+1]*nu3;
            p.z = u[0][4*ch+2]*nu0 + u[1][4*ch+2]*nu1 + u[2][4*ch+2]*nu2 + u[3][4*ch+2]*nu3;
            p.w = u[0][4*ch+3]*nu0 + u[1][4*ch+3]*nu1 + u[2][4*ch+3]*nu2 + u[3][4*ch+3]*nu3;
            *(float4*)&part[w * 1024 + 4 * l + 256 * ch] = p;
        }
        __syncthreads();   // S1: slabs complete

        // column sums across 16 slabs (wide: all 16 waves, conflict-free b32);
        // ONE contiguous f32 atomic per thread (wave = 4 whole cache lines)
        const int buf = it & 3;
        {
            float ssum = 0.f;
            #pragma unroll
            for (int w2 = 0; w2 < 16; ++w2)
                ssum += part[w2 * 1024 + tid];
            unsafeAtomicAdd(&mu_den[((size_t)buf * B_ + b) * N_ + tid], ssum);
        }

        // ---- fence-free flag-vector barrier among the 16 blocks of b ----
        __syncthreads();   // S2: each wave's vmcnt(0) -> adds at coherence pt
        if (tid == 0)      // arrival: plain coherent store (no RMW serialize)
            __hip_atomic_store(&flags[b * 64 + g], (unsigned)(it + 1),
                               __ATOMIC_RELAXED, __HIP_MEMORY_SCOPE_AGENT);
        {   // every wave polls independently (no S3): lanes 0-15 load the 16
            // flags (one line, one wave-instr), ballot until all >= it+1
            const unsigned want = (unsigned)(it + 1);
            while (true) {
                unsigned fv = (l < 16)
                    ? __hip_atomic_load(&flags[b * 64 + l],
                                        __ATOMIC_RELAXED, __HIP_MEMORY_SCOPE_AGENT)
                    : want;
                if (__ballot(fv >= want) == ~0ull) break;
                __builtin_amdgcn_s_sleep(1);
            }
        }

        // ---- per-wave readback -> new mu; zero the buffer for iter it+2 ----
        {
            float den = __hip_atomic_load(&mu_den[((size_t)buf * B_ + b) * N_ + tid],
                                          __ATOMIC_RELAXED, __HIP_MEMORY_SCOPE_AGENT);
            mu_s[tid] = fast_div(cons, den);
        }
        if (tid < 64)   // my block's 1/16 share of the buffer reused at it+2
            __hip_atomic_store(&mu_den[((size_t)((it + 2) & 3) * B_ + b) * N_ + 64 * g + tid],
                               0.0f, __ATOMIC_RELAXED, __HIP_MEMORY_SCOPE_AGENT);
        __syncthreads();   // S4: mu_s ready for next phase A
    }

    // ---- epilogue: T_ij = mu_i * U_ij * nu_j (float4 stores) ----
    float mu_i[4];
    #pragma unroll
    for (int rr = 0; rr < 4; ++rr)
        mu_i[rr] = mu_s[row0 + rr];          // broadcast read

    float* ob = out + (size_t)b * N_ * N_ + (size_t)row0 * N_;
    #pragma unroll
    for (int ch = 0; ch < 4; ++ch) {
        const int cbase = b * N_ + 4 * l + 256 * ch;
        float4 nuv;
        nuv.x = __hip_atomic_load(&nug[cbase + 0], __ATOMIC_RELAXED, __HIP_MEMORY_SCOPE_AGENT);
        nuv.y = __hip_atomic_load(&nug[cbase + 1], __ATOMIC_RELAXED, __HIP_MEMORY_SCOPE_AGENT);
        nuv.z = __hip_atomic_load(&nug[cbase + 2], __ATOMIC_RELAXED, __HIP_MEMORY_SCOPE_AGENT);
        nuv.w = __hip_atomic_load(&nug[cbase + 3], __ATOMIC_RELAXED, __HIP_MEMORY_SCOPE_AGENT);
        #pragma unroll
        for (int rr = 0; rr < 4; ++rr) {
            float4 t;
            t.x = mu_i[rr] * u[rr][4*ch+0] * nuv.x;
            t.y = mu_i[rr] * u[rr][4*ch+1] * nuv.y;
            t.z = mu_i[rr] * u[rr][4*ch+2] * nuv.z;
            t.w = mu_i[rr] * u[rr][4*ch+3] * nuv.w;
            *(float4*)(ob + (size_t)rr * N_ + 4 * l + 256 * ch) = t;
        }
    }
}

extern "C" void kernel_launch(void* const* d_in, const int* in_sizes, int n_in,
                              void* d_out, int out_size, void* d_ws, size_t ws_size,
                              hipStream_t stream) {
    const float* C = (const float*)d_in[2];     // (B, N, N); x,y unused
    float* out = (float*)d_out;

    unsigned char* ws = (unsigned char*)d_ws;
    unsigned int* flags = (unsigned int*)ws;
    float* mu_den = (float*)(ws + MUDEN_OFF);
    float* nug    = (float*)(ws + NUG_OFF);

    // flags + mu_den buffers must start at zero (buffers 2,3 are re-zeroed
    // in-kernel during iters 0,1 as part of the rotation anyway)
    hipMemsetAsync(ws, 0, ZERO_BYTES, stream);
    hipLaunchKernelGGL(sinkhorn_kernel, dim3(256), dim3(1024), 0, stream,
                       C, out, mu_den, nug, flags);
}

// Round 7
// 377.370 us; speedup vs baseline: 1.5821x; 1.0754x over previous
//
#include <hip/hip_runtime.h>
#include <math.h>

#define B_    16
#define N_    1024
#define G_    16      // blocks per batch
#define NW    8       // waves per block (R12: 8 rows/wave)
#define ITERS 100

// ws layout: [cnt: B_*ITERS u32, pad to 8192][mu_den: 4*B_*N_ f32][nug: B_*N_ f32]
#define MUDEN_OFF   8192
#define MUDEN_BYTES (4 * B_ * N_ * 4)
#define NUG_OFF     (MUDEN_OFF + MUDEN_BYTES)
#define ZERO_BYTES  NUG_OFF     // cnt + all 4 mu_den buffers start at 0

__device__ __forceinline__ float fast_div(float num, float den) {
    float r = __builtin_amdgcn_rcpf(den);
    r = r * (2.0f - den * r);      // one Newton step -> ~full fp32 accuracy
    return num * r;
}

// Full 64-lane wave sum via DPP (zero DS-pipe ops, pure VALU). Proven R1-R6.
__device__ __forceinline__ float wave_sum64(float x) {
#define DPP_ADD(ctrl)                                                   \
    x += __int_as_float(__builtin_amdgcn_update_dpp(                    \
            0, __float_as_int(x), ctrl, 0xf, 0xf, false));
    DPP_ADD(0x111)  // row_shr:1
    DPP_ADD(0x112)  // row_shr:2
    DPP_ADD(0x114)  // row_shr:4
    DPP_ADD(0x118)  // row_shr:8
    DPP_ADD(0x142)  // row_bcast:15
    DPP_ADD(0x143)  // row_bcast:31
#undef DPP_ADD
    return __int_as_float(__builtin_amdgcn_readlane(__float_as_int(x), 63));
}

// R12 = R8's proven phases + counter barrier (R11's flag barrier regressed
// 308->326: exchange cost is ~0.45us/iter in any phrasing), re-geometried to
// 8 ROWS PER WAVE: 512-thread blocks, 8 waves, block still owns 64 rows.
// Rationale: each wave reads the FULL mu (4KB) once regardless of its row
// count, so halving wave count halves all DS volume (PhiA 768->384, slab
// 768->384, gather 1488->742 cyc/CU/iter) at constant FMA work. u[8][16]
// costs 128 VGPR; __launch_bounds__(512,2) caps VGPR at 256 -> exactly
// 8 waves/CU, 1 block/CU (no convoy, R9 lesson). All access patterns keep
// the proven lane-contiguous forms: slab write = 16B-stride b128, gather =
// stride-1 b32, atomics at tid / tid+512 (whole cache lines, R7 lesson).
// Ordering (validated R4/R5/R8): __syncthreads() drains vmcnt per wave before
// s_barrier, so atomics are at the L2 coherence point before tid 0's arrival
// add; readers use coherent atomic loads only after the poll sees 16 arrivals.
__global__ __launch_bounds__(512, 2)
void sinkhorn_kernel(const float* __restrict__ C, float* __restrict__ out,
                     float* __restrict__ mu_den, float* __restrict__ nug,
                     unsigned int* __restrict__ cnt)
{
    __shared__ float part[NW * 1024];   // 32 KB: per-wave column-partial slabs
    __shared__ float mu_s[N_];          // 4 KB: current mu

    const int tid = threadIdx.x;
    const int w   = tid >> 6;        // wave 0..7 -> 8-row group
    const int l   = tid & 63;
    // XCD-affinity swizzle: batch b's 16 blocks share bid%8 -> same XCD L2
    const int bid = blockIdx.x;
    const int xx = bid & 7, ss = bid >> 3;
    const int b = xx + ((ss >> 4) << 3);
    const int g = ss & 15;
    const int row0 = 64 * g + 8 * w;
    const float cons = 1.0f / 1024.0f;

    // ---- one-time: U tile = exp(-C/eps), columns 4*l + s + 256*ch ----
    float u[8][16];
    {
        const float* Cb = C + (size_t)b * N_ * N_ + (size_t)row0 * N_;
        #pragma unroll
        for (int rr = 0; rr < 8; ++rr)
            #pragma unroll
            for (int ch = 0; ch < 4; ++ch) {
                float4 cv = *(const float4*)(Cb + (size_t)rr * N_ + 4 * l + 256 * ch);
                u[rr][4*ch+0] = expf(-20.0f * cv.x);
                u[rr][4*ch+1] = expf(-20.0f * cv.y);
                u[rr][4*ch+2] = expf(-20.0f * cv.z);
                u[rr][4*ch+3] = expf(-20.0f * cv.w);
            }
    }

    mu_s[tid]       = cons;
    mu_s[tid + 512] = cons;
    __syncthreads();

    for (int it = 0; it < ITERS; ++it) {
        // ---- Phase A: s_i = sum_j U_ij * mu_j (4x ds_read_b128) ----
        float a0 = 0.f, a1 = 0.f, a2 = 0.f, a3 = 0.f;
        float a4 = 0.f, a5 = 0.f, a6 = 0.f, a7 = 0.f;
        #pragma unroll
        for (int ch = 0; ch < 4; ++ch) {
            float4 mv = *(const float4*)&mu_s[4 * l + 256 * ch];
#define PHA(rr) a##rr += u[rr][4*ch+0]*mv.x + u[rr][4*ch+1]*mv.y \
                       + u[rr][4*ch+2]*mv.z + u[rr][4*ch+3]*mv.w;
            PHA(0) PHA(1) PHA(2) PHA(3) PHA(4) PHA(5) PHA(6) PHA(7)
#undef PHA
        }
        a0 = wave_sum64(a0); a1 = wave_sum64(a1);
        a2 = wave_sum64(a2); a3 = wave_sum64(a3);
        a4 = wave_sum64(a4); a5 = wave_sum64(a5);
        a6 = wave_sum64(a6); a7 = wave_sum64(a7);
        float nu0 = fast_div(cons, a0), nu1 = fast_div(cons, a1);
        float nu2 = fast_div(cons, a2), nu3 = fast_div(cons, a3);
        float nu4 = fast_div(cons, a4), nu5 = fast_div(cons, a5);
        float nu6 = fast_div(cons, a6), nu7 = fast_div(cons, a7);

        if (it == ITERS - 1 && l < 8) {   // publish final nu chunk (coherent)
            float nv = (l == 0) ? nu0 : (l == 1) ? nu1 : (l == 2) ? nu2 :
                       (l == 3) ? nu3 : (l == 4) ? nu4 : (l == 5) ? nu5 :
                       (l == 6) ? nu6 : nu7;
            __hip_atomic_store(&nug[b * N_ + row0 + l], nv,
                               __ATOMIC_RELAXED, __HIP_MEMORY_SCOPE_AGENT);
        }

        // ---- Phase B: per-wave column partials -> slab (4x ds_write_b128,
        //      lane-contiguous 16B stride) ----
        // (no sync needed before this: iter it-1's gather reads finished
        //  before S2 of it-1 < here; part[] and mu_s[] are separate arrays)
        #pragma unroll
        for (int ch = 0; ch < 4; ++ch) {
            float4 p;
#define PB(s) (u[0][4*ch+s]*nu0 + u[1][4*ch+s]*nu1 + u[2][4*ch+s]*nu2 + \
               u[3][4*ch+s]*nu3 + u[4][4*ch+s]*nu4 + u[5][4*ch+s]*nu5 + \
               u[6][4*ch+s]*nu6 + u[7][4*ch+s]*nu7)
            p.x = PB(0); p.y = PB(1); p.z = PB(2); p.w = PB(3);
#undef PB
            *(float4*)&part[w * 1024 + 4 * l + 256 * ch] = p;
        }
        __syncthreads();   // S1: slabs complete

        // column sums across 8 slabs (wide: all 8 waves, conflict-free b32,
        // 2 columns per thread); TWO contiguous f32 atomics per thread
        const int buf = it & 3;
        {
            float s0 = 0.f, s1 = 0.f;
            #pragma unroll
            for (int w2 = 0; w2 < NW; ++w2) {
                s0 += part[w2 * 1024 + tid];
                s1 += part[w2 * 1024 + tid + 512];
            }
            float* md = &mu_den[((size_t)buf * B_ + b) * N_];
            unsafeAtomicAdd(md + tid,       s0);
            unsafeAtomicAdd(md + tid + 512, s1);
        }

        // ---- fence-free device barrier among the 16 blocks of batch b ----
        __syncthreads();   // S2: each wave's vmcnt(0) -> adds at coherence pt
        if (tid == 0) {
            unsigned int* c = &cnt[b * ITERS + it];
            __hip_atomic_fetch_add(c, 1u, __ATOMIC_RELAXED, __HIP_MEMORY_SCOPE_AGENT);
            while (__hip_atomic_load(c, __ATOMIC_RELAXED, __HIP_MEMORY_SCOPE_AGENT) < G_)
                __builtin_amdgcn_s_sleep(1);
        }
        __syncthreads();   // S3

        // ---- readback -> new mu; zero the buffer for iter it+2 ----
        {
            const float* mdb = &mu_den[((size_t)buf * B_ + b) * N_];
            float den0 = __hip_atomic_load(mdb + tid,
                                           __ATOMIC_RELAXED, __HIP_MEMORY_SCOPE_AGENT);
            float den1 = __hip_atomic_load(mdb + tid + 512,
                                           __ATOMIC_RELAXED, __HIP_MEMORY_SCOPE_AGENT);
            mu_s[tid]       = fast_div(cons, den0);
            mu_s[tid + 512] = fast_div(cons, den1);
        }
        if (tid < 64)   // my block's 1/16 share of the buffer reused at it+2
            __hip_atomic_store(&mu_den[((size_t)((it + 2) & 3) * B_ + b) * N_ + 64 * g + tid],
                               0.0f, __ATOMIC_RELAXED, __HIP_MEMORY_SCOPE_AGENT);
        __syncthreads();   // S4: mu_s ready for next phase A
    }

    // ---- epilogue: T_ij = mu_i * U_ij * nu_j (float4 stores) ----
    float mu_i[8];
    #pragma unroll
    for (int rr = 0; rr < 8; ++rr)
        mu_i[rr] = mu_s[row0 + rr];          // broadcast read

    float* ob = out + (size_t)b * N_ * N_ + (size_t)row0 * N_;
    #pragma unroll
    for (int ch = 0; ch < 4; ++ch) {
        const int cbase = b * N_ + 4 * l + 256 * ch;
        float4 nuv;
        nuv.x = __hip_atomic_load(&nug[cbase + 0], __ATOMIC_RELAXED, __HIP_MEMORY_SCOPE_AGENT);
        nuv.y = __hip_atomic_load(&nug[cbase + 1], __ATOMIC_RELAXED, __HIP_MEMORY_SCOPE_AGENT);
        nuv.z = __hip_atomic_load(&nug[cbase + 2], __ATOMIC_RELAXED, __HIP_MEMORY_SCOPE_AGENT);
        nuv.w = __hip_atomic_load(&nug[cbase + 3], __ATOMIC_RELAXED, __HIP_MEMORY_SCOPE_AGENT);
        #pragma unroll
        for (int rr = 0; rr < 8; ++rr) {
            float4 t;
            t.x = mu_i[rr] * u[rr][4*ch+0] * nuv.x;
            t.y = mu_i[rr] * u[rr][4*ch+1] * nuv.y;
            t.z = mu_i[rr] * u[rr][4*ch+2] * nuv.z;
            t.w = mu_i[rr] * u[rr][4*ch+3] * nuv.w;
            *(float4*)(ob + (size_t)rr * N_ + 4 * l + 256 * ch) = t;
        }
    }
}

extern "C" void kernel_launch(void* const* d_in, const int* in_sizes, int n_in,
                              void* d_out, int out_size, void* d_ws, size_t ws_size,
                              hipStream_t stream) {
    const float* C = (const float*)d_in[2];     // (B, N, N); x,y unused
    float* out = (float*)d_out;

    unsigned char* ws = (unsigned char*)d_ws;
    unsigned int* cnt = (unsigned int*)ws;
    float* mu_den = (float*)(ws + MUDEN_OFF);
    float* nug    = (float*)(ws + NUG_OFF);

    // cnt + mu_den buffers must start at zero (buffers 2,3 are re-zeroed
    // in-kernel during iters 0,1 as part of the rotation anyway)
    hipMemsetAsync(ws, 0, ZERO_BYTES, stream);
    hipLaunchKernelGGL(sinkhorn_kernel, dim3(256), dim3(512), 0, stream,
                       C, out, mu_den, nug, cnt);
}